// Round 1
// baseline (326.587 us; speedup 1.0000x reference)
//
#include <hip/hip_runtime.h>

// Causal self-attention fwd: B=2 S=4096 H=16 D=64, fp32 in/out, bf16 MFMA compute.
// Design:
//  - QBLK=128 (4 waves x 32 q-rows), KVBLK=64, flash-style online softmax (log2 domain).
//  - Swapped QK^T: mfma_16x16x32_bf16(A=K, B=Q) -> C[kv][q]; per-lane column q=lane&15.
//  - PV uses mfma_16x16x16_bf16: swapped-C row mapping (kv=4*(l>>4)+r) == A-frag k mapping
//    (k=4*(l>>4)+j), so P goes regs->MFMA directly (no LDS round-trip / no shuffles).
//  - K in LDS row-major [64][72] (pad 72 keeps 16B alignment, spreads banks);
//    V in LDS transposed VT[d][kv] so PV B-frags are contiguous b64 reads.
//  - Reg-prefetch next K/V tile before compute to hide HBM latency.

#define S_LEN 4096
#define NHEAD 16
#define HDIM 64
#define QBLK 128
#define KVBLK 64
#define LDK 72
#define ROWSTRIDE (3 * NHEAD * HDIM)  // 3072 floats between consecutive s

using bf16x8 = __attribute__((ext_vector_type(8))) short;
using bf16x4 = __attribute__((ext_vector_type(4))) short;
using f32x4  = __attribute__((ext_vector_type(4))) float;

#define MFMA32(A, B, C) __builtin_amdgcn_mfma_f32_16x16x32_bf16((A), (B), (C), 0, 0, 0)
#define MFMA16(A, B, C) __builtin_amdgcn_mfma_f32_16x16x16bf16_1k((A), (B), (C), 0, 0, 0)

#if __has_builtin(__builtin_amdgcn_exp2f)
#define EXP2F(x) __builtin_amdgcn_exp2f(x)
#else
#define EXP2F(x) exp2f(x)
#endif

__device__ __forceinline__ short f2bf(float x) {
  unsigned u = __builtin_bit_cast(unsigned, x);
  u += 0x7FFFu + ((u >> 16) & 1u);  // RNE to bf16 (inputs are normal floats)
  return (short)(u >> 16);
}

__global__ __launch_bounds__(256, 2)
void attn_fwd(const float* __restrict__ qkv, float* __restrict__ out) {
  __shared__ short Ks[KVBLK][LDK] __attribute__((aligned(16)));   // K[kv][d] bf16
  __shared__ short VTs[HDIM][LDK] __attribute__((aligned(16)));   // V^T[d][kv] bf16

  const int qt   = blockIdx.x;
  const int bh   = blockIdx.y;
  const int b    = bh >> 4;   // H=16
  const int h    = bh & 15;
  const int tid  = threadIdx.x;
  const int wid  = tid >> 6;
  const int lane = tid & 63;
  const int lq   = lane & 15;
  const int lg   = lane >> 4;

  const int qbase = qt * QBLK;
  const int wq    = qbase + wid * 32;  // this wave's first q row

  const float* basep = qkv + (size_t)b * S_LEN * ROWSTRIDE;
  const float* kbase = basep + NHEAD * HDIM;       // t=1
  const float* vbase = basep + 2 * NHEAD * HDIM;   // t=2

  // ---- Q fragments (B-operand layout: col=q=lq, k=d=8*lg+j+32*t); scale folded, log2 dom ----
  const float SC = 0.18033688011112042f;  // (1/8) * log2(e)
  bf16x8 qf[2][2];
#pragma unroll
  for (int rt = 0; rt < 2; ++rt) {
    const float* qp = basep + (size_t)(wq + rt * 16 + lq) * ROWSTRIDE + h * HDIM + 8 * lg;
#pragma unroll
    for (int t = 0; t < 2; ++t) {
      f32x4 x0 = *reinterpret_cast<const f32x4*>(qp + 32 * t);
      f32x4 x1 = *reinterpret_cast<const f32x4*>(qp + 32 * t + 4);
      bf16x8 f;
      f[0] = f2bf(x0[0] * SC); f[1] = f2bf(x0[1] * SC);
      f[2] = f2bf(x0[2] * SC); f[3] = f2bf(x0[3] * SC);
      f[4] = f2bf(x1[0] * SC); f[5] = f2bf(x1[1] * SC);
      f[6] = f2bf(x1[2] * SC); f[7] = f2bf(x1[3] * SC);
      qf[rt][t] = f;
    }
  }

  // ---- staging assignment: 4 kv-rows x 4 d-cols per thread (enables short4 LDS writes) ----
  const int rb = (tid >> 4) * 4;  // kv row base within tile
  const int cb = (tid & 15) * 4;  // d col base

  f32x4 kreg[4], vreg[4];
  auto load_tile = [&](int kvt) {
    const int kr = kvt * KVBLK + rb;
#pragma unroll
    for (int i = 0; i < 4; ++i) {
      kreg[i] = *reinterpret_cast<const f32x4*>(kbase + (size_t)(kr + i) * ROWSTRIDE + h * HDIM + cb);
      vreg[i] = *reinterpret_cast<const f32x4*>(vbase + (size_t)(kr + i) * ROWSTRIDE + h * HDIM + cb);
    }
  };

  f32x4 acc[2][4];
#pragma unroll
  for (int rt = 0; rt < 2; ++rt)
#pragma unroll
    for (int dt = 0; dt < 4; ++dt)
      acc[rt][dt] = (f32x4){0.f, 0.f, 0.f, 0.f};

  float mrun[2] = {-1e30f, -1e30f};
  float lrun[2] = {0.f, 0.f};

  const int nkv = 2 * qt + 2;  // causal: kv tiles 0 .. 2*qt+1
  load_tile(0);

  for (int kvt = 0; kvt < nkv; ++kvt) {
    __syncthreads();  // previous tile's LDS reads complete
    // write staged tile to LDS (convert bf16; V transposed via register 4x4 transpose)
#pragma unroll
    for (int i = 0; i < 4; ++i) {
      bf16x4 kk;
      kk[0] = f2bf(kreg[i][0]); kk[1] = f2bf(kreg[i][1]);
      kk[2] = f2bf(kreg[i][2]); kk[3] = f2bf(kreg[i][3]);
      *reinterpret_cast<bf16x4*>(&Ks[rb + i][cb]) = kk;
    }
#pragma unroll
    for (int e = 0; e < 4; ++e) {
      bf16x4 vv;
      vv[0] = f2bf(vreg[0][e]); vv[1] = f2bf(vreg[1][e]);
      vv[2] = f2bf(vreg[2][e]); vv[3] = f2bf(vreg[3][e]);
      *reinterpret_cast<bf16x4*>(&VTs[cb + e][rb]) = vv;
    }
    __syncthreads();  // tile visible to all waves

    if (kvt + 1 < nkv) load_tile(kvt + 1);  // prefetch overlaps compute

    const int kvb = kvt * KVBLK;
    if (kvb > wq + 31) continue;  // tile fully masked for this wave's rows

    // ---- QK^T (swapped: A=K, B=Q -> C[kv=4*lg+r][q=lq]) ----
    f32x4 sc[2][4];
#pragma unroll
    for (int rt = 0; rt < 2; ++rt)
#pragma unroll
      for (int c = 0; c < 4; ++c)
        sc[rt][c] = (f32x4){0.f, 0.f, 0.f, 0.f};

#pragma unroll
    for (int c = 0; c < 4; ++c) {
      bf16x8 k0 = *reinterpret_cast<const bf16x8*>(&Ks[c * 16 + lq][8 * lg]);
      bf16x8 k1 = *reinterpret_cast<const bf16x8*>(&Ks[c * 16 + lq][8 * lg + 32]);
#pragma unroll
      for (int rt = 0; rt < 2; ++rt) {
        sc[rt][c] = MFMA32(k0, qf[rt][0], sc[rt][c]);
        sc[rt][c] = MFMA32(k1, qf[rt][1], sc[rt][c]);
      }
    }

    // causal mask (only the <=2 diagonal tiles of each wave trigger this)
    if (kvb + KVBLK - 1 > wq) {
#pragma unroll
      for (int rt = 0; rt < 2; ++rt) {
        const int q0 = wq + rt * 16 + lq;
#pragma unroll
        for (int c = 0; c < 4; ++c)
#pragma unroll
          for (int r = 0; r < 4; ++r)
            if (kvb + c * 16 + 4 * lg + r > q0) sc[rt][c][r] = -1e30f;
      }
    }

    // ---- online softmax, P stays in registers (A-frag layout == C layout) ----
    bf16x4 pf[2][4];
    float alpha[2];
#pragma unroll
    for (int rt = 0; rt < 2; ++rt) {
      float c0 = fmaxf(fmaxf(sc[rt][0][0], sc[rt][0][1]), fmaxf(sc[rt][0][2], sc[rt][0][3]));
      float c1 = fmaxf(fmaxf(sc[rt][1][0], sc[rt][1][1]), fmaxf(sc[rt][1][2], sc[rt][1][3]));
      float c2 = fmaxf(fmaxf(sc[rt][2][0], sc[rt][2][1]), fmaxf(sc[rt][2][2], sc[rt][2][3]));
      float c3 = fmaxf(fmaxf(sc[rt][3][0], sc[rt][3][1]), fmaxf(sc[rt][3][2], sc[rt][3][3]));
      float tm = fmaxf(fmaxf(c0, c1), fmaxf(c2, c3));
      tm = fmaxf(tm, __shfl_xor(tm, 16));
      tm = fmaxf(tm, __shfl_xor(tm, 32));
      const float newm = fmaxf(mrun[rt], tm);
      alpha[rt] = EXP2F(mrun[rt] - newm);
      mrun[rt] = newm;

      float ts = 0.f;
#pragma unroll
      for (int c = 0; c < 4; ++c) {
        float p0 = EXP2F(sc[rt][c][0] - newm);
        float p1 = EXP2F(sc[rt][c][1] - newm);
        float p2 = EXP2F(sc[rt][c][2] - newm);
        float p3 = EXP2F(sc[rt][c][3] - newm);
        ts += (p0 + p1) + (p2 + p3);
        bf16x4 pp;
        pp[0] = f2bf(p0); pp[1] = f2bf(p1); pp[2] = f2bf(p2); pp[3] = f2bf(p3);
        pf[rt][c] = pp;
      }
      ts += __shfl_xor(ts, 16);
      ts += __shfl_xor(ts, 32);
      lrun[rt] = lrun[rt] * alpha[rt] + ts;
    }

    // ---- rescale acc: alpha lives per q=lq, acc rows are q=4*lg+r -> fetch via shfl ----
#pragma unroll
    for (int rt = 0; rt < 2; ++rt) {
      const float a0 = __shfl(alpha[rt], 4 * lg + 0);
      const float a1 = __shfl(alpha[rt], 4 * lg + 1);
      const float a2 = __shfl(alpha[rt], 4 * lg + 2);
      const float a3 = __shfl(alpha[rt], 4 * lg + 3);
#pragma unroll
      for (int dt = 0; dt < 4; ++dt) {
        acc[rt][dt][0] *= a0;
        acc[rt][dt][1] *= a1;
        acc[rt][dt][2] *= a2;
        acc[rt][dt][3] *= a3;
      }
    }

    // ---- PV: A=P from regs, B=V from VT (contiguous b64 reads), C[q=4*lg+r][d=lq] ----
#pragma unroll
    for (int dt = 0; dt < 4; ++dt) {
#pragma unroll
      for (int c = 0; c < 4; ++c) {
        bf16x4 vf = *reinterpret_cast<const bf16x4*>(&VTs[dt * 16 + lq][c * 16 + 4 * lg]);
        acc[0][dt] = MFMA16(pf[0][c], vf, acc[0][dt]);
        acc[1][dt] = MFMA16(pf[1][c], vf, acc[1][dt]);
      }
    }
  }

  // ---- epilogue: normalize and store (fp32 out) ----
#pragma unroll
  for (int rt = 0; rt < 2; ++rt) {
    const float l0 = __shfl(lrun[rt], 4 * lg + 0);
    const float l1 = __shfl(lrun[rt], 4 * lg + 1);
    const float l2 = __shfl(lrun[rt], 4 * lg + 2);
    const float l3 = __shfl(lrun[rt], 4 * lg + 3);
    const f32x4 linv = {1.f / l0, 1.f / l1, 1.f / l2, 1.f / l3};
#pragma unroll
    for (int dt = 0; dt < 4; ++dt) {
#pragma unroll
      for (int r = 0; r < 4; ++r) {
        out[(size_t)(b * S_LEN + wq + rt * 16 + 4 * lg + r) * (NHEAD * HDIM) + h * HDIM + dt * 16 + lq] =
            acc[rt][dt][r] * linv[r];
      }
    }
  }
}

extern "C" void kernel_launch(void* const* d_in, const int* in_sizes, int n_in,
                              void* d_out, int out_size, void* d_ws, size_t ws_size,
                              hipStream_t stream) {
  const float* qkv = (const float*)d_in[0];
  float* o = (float*)d_out;
  dim3 grid(S_LEN / QBLK, 2 * NHEAD);  // (q tiles, B*H)
  attn_fwd<<<grid, 256, 0, stream>>>(qkv, o);
}

// Round 3
// 173.886 us; speedup vs baseline: 1.8782x; 1.8782x over previous
//
#include <hip/hip_runtime.h>

// Causal self-attention fwd: B=2 S=4096 H=16 D=64, fp32 in/out, bf16 MFMA compute.
// R3 = R2 with the f2bf2 compile fix (inline-asm v_cvt_pk_bf16_f32; no builtin on gfx950).
//  - Causal load balance: each block processes q-tiles {qt, 31-qt} -> uniform 66 kv-steps.
//    Grid (16,32)=512 blocks, 2/CU, all co-resident and uniformly busy.
//  - 512 threads (8 waves x 16 q-rows). K staged by threads 0-255, V by 256-511.
//  - Packed bf16 converts via v_cvt_pk_bf16_f32.
//  - Exact defer-max: skip alpha/rescale when no row max grew.

#define S_LEN 4096
#define NHEAD 16
#define HDIM 64
#define QBLK 128
#define KVBLK 64
#define NQT (S_LEN / QBLK)  // 32
#define LDK 72
#define ROWSTRIDE (3 * NHEAD * HDIM)  // 3072 floats between consecutive s

using bf16x8 = __attribute__((ext_vector_type(8))) short;
using bf16x4 = __attribute__((ext_vector_type(4))) short;
using f32x4  = __attribute__((ext_vector_type(4))) float;

#define MFMA32(A, B, C) __builtin_amdgcn_mfma_f32_16x16x32_bf16((A), (B), (C), 0, 0, 0)
#define MFMA16(A, B, C) __builtin_amdgcn_mfma_f32_16x16x16bf16_1k((A), (B), (C), 0, 0, 0)

#if __has_builtin(__builtin_amdgcn_exp2f)
#define EXP2F(x) __builtin_amdgcn_exp2f(x)
#else
#define EXP2F(x) exp2f(x)
#endif

__device__ __forceinline__ int f2bf2(float lo, float hi) {
  int r;
  asm("v_cvt_pk_bf16_f32 %0, %1, %2" : "=v"(r) : "v"(lo), "v"(hi));
  return r;  // low 16 bits = bf16(lo), high 16 = bf16(hi)
}

__global__ __launch_bounds__(512, 4)
void attn_fwd(const float* __restrict__ qkv, float* __restrict__ out) {
  __shared__ short Ks[KVBLK][LDK] __attribute__((aligned(16)));   // K[kv][d] bf16
  __shared__ short VTs[HDIM][LDK] __attribute__((aligned(16)));   // V^T[d][kv] bf16

  const int bh   = blockIdx.y;
  const int b    = bh >> 4;   // H=16
  const int h    = bh & 15;
  const int tid  = threadIdx.x;
  const int wid  = tid >> 6;   // 0..7
  const int lane = tid & 63;
  const int lq   = lane & 15;
  const int lg   = lane >> 4;

  const float* basep = qkv + (size_t)b * S_LEN * ROWSTRIDE + h * HDIM;
  const float* kbase = basep + NHEAD * HDIM;       // t=1
  const float* vbase = basep + 2 * NHEAD * HDIM;   // t=2

  // ---- staging roles: threads 0-255 stage K rows, 256-511 stage V (transposed) ----
  const bool isK = tid < 256;
  const int st   = isK ? tid : tid - 256;
  const int krow = st >> 2;            // K: one row, 16 cols
  const int kcol = (st & 3) * 16;
  const int vrb  = (st >> 4) * 4;      // V: 4 rows x 4 cols micro-tile
  const int vcb  = (st & 15) * 4;

  f32x4 sreg[4];
  auto load_tile = [&](int kvt) {
    if (isK) {
      const float* p = kbase + (size_t)(kvt * KVBLK + krow) * ROWSTRIDE + kcol;
      sreg[0] = *reinterpret_cast<const f32x4*>(p);
      sreg[1] = *reinterpret_cast<const f32x4*>(p + 4);
      sreg[2] = *reinterpret_cast<const f32x4*>(p + 8);
      sreg[3] = *reinterpret_cast<const f32x4*>(p + 12);
    } else {
      const float* p = vbase + (size_t)(kvt * KVBLK + vrb) * ROWSTRIDE + vcb;
#pragma unroll
      for (int i = 0; i < 4; ++i)
        sreg[i] = *reinterpret_cast<const f32x4*>(p + (size_t)i * ROWSTRIDE);
    }
  };
  auto store_tile = [&]() {
    if (isK) {
      union { bf16x8 v; int i[4]; } u0, u1;
      u0.i[0] = f2bf2(sreg[0][0], sreg[0][1]); u0.i[1] = f2bf2(sreg[0][2], sreg[0][3]);
      u0.i[2] = f2bf2(sreg[1][0], sreg[1][1]); u0.i[3] = f2bf2(sreg[1][2], sreg[1][3]);
      u1.i[0] = f2bf2(sreg[2][0], sreg[2][1]); u1.i[1] = f2bf2(sreg[2][2], sreg[2][3]);
      u1.i[2] = f2bf2(sreg[3][0], sreg[3][1]); u1.i[3] = f2bf2(sreg[3][2], sreg[3][3]);
      *reinterpret_cast<bf16x8*>(&Ks[krow][kcol])     = u0.v;
      *reinterpret_cast<bf16x8*>(&Ks[krow][kcol + 8]) = u1.v;
    } else {
#pragma unroll
      for (int e = 0; e < 4; ++e) {
        union { bf16x4 v; int i[2]; } w;
        w.i[0] = f2bf2(sreg[0][e], sreg[1][e]);
        w.i[1] = f2bf2(sreg[2][e], sreg[3][e]);
        *reinterpret_cast<bf16x4*>(&VTs[vcb + e][vrb]) = w.v;
      }
    }
  };

  const float SC = 0.18033688011112042f;  // (1/8) * log2(e)

#pragma unroll 1
  for (int pi = 0; pi < 2; ++pi) {
    const int qt = (pi == 0) ? (int)blockIdx.x : (NQT - 1 - (int)blockIdx.x);
    const int wq = qt * QBLK + wid * 16;  // this wave's first q row

    // ---- Q fragments (B-operand: col=q=lq, k=d=8*lg+j+32*t); scale folded, log2 dom ----
    bf16x8 qf[2];
    {
      const float* qp = basep + (size_t)(wq + lq) * ROWSTRIDE + 8 * lg;
#pragma unroll
      for (int t = 0; t < 2; ++t) {
        f32x4 x0 = *reinterpret_cast<const f32x4*>(qp + 32 * t);
        f32x4 x1 = *reinterpret_cast<const f32x4*>(qp + 32 * t + 4);
        union { bf16x8 v; int i[4]; } u;
        u.i[0] = f2bf2(x0[0] * SC, x0[1] * SC);
        u.i[1] = f2bf2(x0[2] * SC, x0[3] * SC);
        u.i[2] = f2bf2(x1[0] * SC, x1[1] * SC);
        u.i[3] = f2bf2(x1[2] * SC, x1[3] * SC);
        qf[t] = u.v;
      }
    }

    f32x4 acc[4];
#pragma unroll
    for (int dt = 0; dt < 4; ++dt) acc[dt] = (f32x4){0.f, 0.f, 0.f, 0.f};
    float mrun = -1e30f, lrun = 0.f;

    const int nkv = 2 * qt + 2;  // causal: kv tiles 0 .. 2*qt+1
    load_tile(0);

    for (int kvt = 0; kvt < nkv; ++kvt) {
      __syncthreads();   // previous tile's LDS reads complete (also guards pass boundary)
      store_tile();
      __syncthreads();   // tile visible
      if (kvt + 1 < nkv) load_tile(kvt + 1);  // prefetch overlaps compute

      const int kvb = kvt * KVBLK;
      if (kvb > wq + 15) continue;  // tile fully above diagonal for this wave

      // ---- QK^T (swapped: A=K, B=Q -> C[kv=4*lg+r][q=lq]) ----
      f32x4 sc[4];
#pragma unroll
      for (int c = 0; c < 4; ++c) sc[c] = (f32x4){0.f, 0.f, 0.f, 0.f};
#pragma unroll
      for (int c = 0; c < 4; ++c) {
        bf16x8 k0 = *reinterpret_cast<const bf16x8*>(&Ks[c * 16 + lq][8 * lg]);
        bf16x8 k1 = *reinterpret_cast<const bf16x8*>(&Ks[c * 16 + lq][8 * lg + 32]);
        sc[c] = MFMA32(k0, qf[0], sc[c]);
        sc[c] = MFMA32(k1, qf[1], sc[c]);
      }

      // causal mask (diagonal tiles only)
      if (kvb + KVBLK - 1 > wq) {
        const int q0 = wq + lq;
#pragma unroll
        for (int c = 0; c < 4; ++c)
#pragma unroll
          for (int r = 0; r < 4; ++r)
            if (kvb + c * 16 + 4 * lg + r > q0) sc[c][r] = -1e30f;
      }

      // ---- online softmax (per q-row = lane lq), P stays in registers ----
      float c0 = fmaxf(fmaxf(sc[0][0], sc[0][1]), fmaxf(sc[0][2], sc[0][3]));
      float c1 = fmaxf(fmaxf(sc[1][0], sc[1][1]), fmaxf(sc[1][2], sc[1][3]));
      float c2 = fmaxf(fmaxf(sc[2][0], sc[2][1]), fmaxf(sc[2][2], sc[2][3]));
      float c3 = fmaxf(fmaxf(sc[3][0], sc[3][1]), fmaxf(sc[3][2], sc[3][3]));
      float tm = fmaxf(fmaxf(c0, c1), fmaxf(c2, c3));
      tm = fmaxf(tm, __shfl_xor(tm, 16));
      tm = fmaxf(tm, __shfl_xor(tm, 32));

      const bool grow = !__all(tm <= mrun);  // wave-uniform
      float alpha = 1.f;
      if (grow) {
        const float newm = fmaxf(mrun, tm);
        alpha = EXP2F(mrun - newm);
        mrun = newm;
      }

      bf16x4 pf[4];
      float ts = 0.f;
#pragma unroll
      for (int c = 0; c < 4; ++c) {
        float p0 = EXP2F(sc[c][0] - mrun);
        float p1 = EXP2F(sc[c][1] - mrun);
        float p2 = EXP2F(sc[c][2] - mrun);
        float p3 = EXP2F(sc[c][3] - mrun);
        ts += (p0 + p1) + (p2 + p3);
        union { bf16x4 v; int i[2]; } w;
        w.i[0] = f2bf2(p0, p1);
        w.i[1] = f2bf2(p2, p3);
        pf[c] = w.v;
      }
      ts += __shfl_xor(ts, 16);
      ts += __shfl_xor(ts, 32);
      lrun = lrun * alpha + ts;

      if (grow) {  // rescale acc: alpha is per q=lq; acc rows are q=4*lg+r
        const float a0 = __shfl(alpha, 4 * lg + 0);
        const float a1 = __shfl(alpha, 4 * lg + 1);
        const float a2 = __shfl(alpha, 4 * lg + 2);
        const float a3 = __shfl(alpha, 4 * lg + 3);
#pragma unroll
        for (int dt = 0; dt < 4; ++dt) {
          acc[dt][0] *= a0; acc[dt][1] *= a1; acc[dt][2] *= a2; acc[dt][3] *= a3;
        }
      }

      // ---- PV: A=P regs (C-layout == A-frag layout), B=V^T from LDS ----
#pragma unroll
      for (int dt = 0; dt < 4; ++dt) {
#pragma unroll
        for (int c = 0; c < 4; ++c) {
          bf16x4 vf = *reinterpret_cast<const bf16x4*>(&VTs[dt * 16 + lq][c * 16 + 4 * lg]);
          acc[dt] = MFMA16(pf[c], vf, acc[dt]);
        }
      }
    }

    // ---- epilogue: normalize + store (fp32 out), rows q=4*lg+r, col dt*16+lq ----
    const float l0 = __shfl(lrun, 4 * lg + 0);
    const float l1 = __shfl(lrun, 4 * lg + 1);
    const float l2 = __shfl(lrun, 4 * lg + 2);
    const float l3 = __shfl(lrun, 4 * lg + 3);
    const f32x4 linv = {1.f / l0, 1.f / l1, 1.f / l2, 1.f / l3};
#pragma unroll
    for (int dt = 0; dt < 4; ++dt) {
#pragma unroll
      for (int r = 0; r < 4; ++r) {
        out[(size_t)(b * S_LEN + wq + 4 * lg + r) * (NHEAD * HDIM) + h * HDIM + dt * 16 + lq] =
            acc[dt][r] * linv[r];
      }
    }
  }
}

extern "C" void kernel_launch(void* const* d_in, const int* in_sizes, int n_in,
                              void* d_out, int out_size, void* d_ws, size_t ws_size,
                              hipStream_t stream) {
  const float* qkv = (const float*)d_in[0];
  float* o = (float*)d_out;
  dim3 grid(NQT / 2, 2 * NHEAD);  // paired q-tiles x (B*H)
  attn_fwd<<<grid, 512, 0, stream>>>(qkv, o);
}

// Round 6
// 170.169 us; speedup vs baseline: 1.9192x; 1.0218x over previous
//
#include <hip/hip_runtime.h>

// Causal self-attention fwd: B=2 S=4096 H=16 D=64, fp32 in/out, bf16 MFMA compute.
// R6 = union of hardware-validated components ONLY:
//  - R1's compute structure verbatim: rt=2 (32 q-rows/wave), 4 waves x 256 threads,
//    micro-tile (4x4) K and V staging, VALU l-sum + shfl epilogue, unconditional rescale.
//  - R3's causal pairing {qt, 31-qt} (grid (16,32)) and f2bf2 packed bf16 converts.
//  - NO ones-trick, NO merged full-row K staging, NO defer-max (R4/R5 failure suspects).

#define S_LEN 4096
#define NHEAD 16
#define HDIM 64
#define QBLK 128
#define KVBLK 64
#define NQT (S_LEN / QBLK)  // 32
#define LDK 72
#define ROWSTRIDE (3 * NHEAD * HDIM)  // 3072 floats between consecutive s

using bf16x8 = __attribute__((ext_vector_type(8))) short;
using bf16x4 = __attribute__((ext_vector_type(4))) short;
using f32x4  = __attribute__((ext_vector_type(4))) float;

#define MFMA32(A, B, C) __builtin_amdgcn_mfma_f32_16x16x32_bf16((A), (B), (C), 0, 0, 0)
#define MFMA16(A, B, C) __builtin_amdgcn_mfma_f32_16x16x16bf16_1k((A), (B), (C), 0, 0, 0)

#if __has_builtin(__builtin_amdgcn_exp2f)
#define EXP2F(x) __builtin_amdgcn_exp2f(x)
#else
#define EXP2F(x) exp2f(x)
#endif

__device__ __forceinline__ int f2bf2(float lo, float hi) {
  int r;
  asm("v_cvt_pk_bf16_f32 %0, %1, %2" : "=v"(r) : "v"(lo), "v"(hi));
  return r;  // low 16 = bf16(lo), high 16 = bf16(hi)
}

__global__ __launch_bounds__(256, 2)
void attn_fwd(const float* __restrict__ qkv, float* __restrict__ out) {
  __shared__ short Ks[KVBLK][LDK] __attribute__((aligned(16)));   // K[kv][d] bf16
  __shared__ short VTs[HDIM][LDK] __attribute__((aligned(16)));   // V^T[d][kv] bf16

  const int bh   = blockIdx.y;
  const int b    = bh >> 4;   // H=16
  const int h    = bh & 15;
  const int tid  = threadIdx.x;
  const int wid  = tid >> 6;   // 0..3
  const int lane = tid & 63;
  const int lq   = lane & 15;
  const int lg   = lane >> 4;

  const float* basep = qkv + (size_t)b * S_LEN * ROWSTRIDE + h * HDIM;
  const float* kbase = basep + NHEAD * HDIM;       // t=1
  const float* vbase = basep + 2 * NHEAD * HDIM;   // t=2

  // ---- staging (R1-validated): each thread owns a 4x4 micro-tile of K and of V ----
  const int rb = (tid >> 4) * 4;  // kv row base within tile
  const int cb = (tid & 15) * 4;  // d col base

  f32x4 kreg[4], vreg[4];
  auto load_tile = [&](int kvt) {
    const int kr = kvt * KVBLK + rb;
#pragma unroll
    for (int i = 0; i < 4; ++i) {
      kreg[i] = *reinterpret_cast<const f32x4*>(kbase + (size_t)(kr + i) * ROWSTRIDE + cb);
      vreg[i] = *reinterpret_cast<const f32x4*>(vbase + (size_t)(kr + i) * ROWSTRIDE + cb);
    }
  };
  auto store_tile = [&]() {
#pragma unroll
    for (int i = 0; i < 4; ++i) {
      union { bf16x4 v; int w[2]; } kk;
      kk.w[0] = f2bf2(kreg[i][0], kreg[i][1]);
      kk.w[1] = f2bf2(kreg[i][2], kreg[i][3]);
      *reinterpret_cast<bf16x4*>(&Ks[rb + i][cb]) = kk.v;
    }
#pragma unroll
    for (int e = 0; e < 4; ++e) {
      union { bf16x4 v; int w[2]; } vv;
      vv.w[0] = f2bf2(vreg[0][e], vreg[1][e]);
      vv.w[1] = f2bf2(vreg[2][e], vreg[3][e]);
      *reinterpret_cast<bf16x4*>(&VTs[cb + e][rb]) = vv.v;
    }
  };

  const float SC = 0.18033688011112042f;  // (1/8) * log2(e)

#pragma unroll 1
  for (int pi = 0; pi < 2; ++pi) {
    const int qt = (pi == 0) ? (int)blockIdx.x : (NQT - 1 - (int)blockIdx.x);
    const int wq = qt * QBLK + wid * 32;  // this wave's first q row (32 rows)

    // ---- Q fragments (B-operand: col=q=lq, k=d=8*lg+j+32*t) for rt=0,1 ----
    bf16x8 qf[2][2];
#pragma unroll
    for (int rt = 0; rt < 2; ++rt) {
      const float* qp = basep + (size_t)(wq + rt * 16 + lq) * ROWSTRIDE + 8 * lg;
#pragma unroll
      for (int t = 0; t < 2; ++t) {
        f32x4 x0 = *reinterpret_cast<const f32x4*>(qp + 32 * t);
        f32x4 x1 = *reinterpret_cast<const f32x4*>(qp + 32 * t + 4);
        union { bf16x8 v; int w[4]; } u;
        u.w[0] = f2bf2(x0[0] * SC, x0[1] * SC);
        u.w[1] = f2bf2(x0[2] * SC, x0[3] * SC);
        u.w[2] = f2bf2(x1[0] * SC, x1[1] * SC);
        u.w[3] = f2bf2(x1[2] * SC, x1[3] * SC);
        qf[rt][t] = u.v;
      }
    }

    f32x4 acc[2][4];
#pragma unroll
    for (int rt = 0; rt < 2; ++rt)
#pragma unroll
      for (int dt = 0; dt < 4; ++dt)
        acc[rt][dt] = (f32x4){0.f, 0.f, 0.f, 0.f};

    float mrun[2] = {-1e30f, -1e30f};
    float lrun[2] = {0.f, 0.f};

    const int nkv = 2 * qt + 2;  // causal: kv tiles 0 .. 2*qt+1
    load_tile(0);

    for (int kvt = 0; kvt < nkv; ++kvt) {
      __syncthreads();  // previous tile's LDS reads complete (also guards pass boundary)
      store_tile();
      __syncthreads();  // tile visible to all waves
      if (kvt + 1 < nkv) load_tile(kvt + 1);  // prefetch overlaps compute

      const int kvb = kvt * KVBLK;
      if (kvb > wq + 31) continue;  // tile fully masked for this wave's rows

      // ---- QK^T (swapped: A=K, B=Q -> C[kv=c*16+4*lg+r][q=lq]) ----
      f32x4 sc[2][4];
#pragma unroll
      for (int rt = 0; rt < 2; ++rt)
#pragma unroll
        for (int c = 0; c < 4; ++c)
          sc[rt][c] = (f32x4){0.f, 0.f, 0.f, 0.f};

#pragma unroll
      for (int c = 0; c < 4; ++c) {
        bf16x8 k0 = *reinterpret_cast<const bf16x8*>(&Ks[c * 16 + lq][8 * lg]);
        bf16x8 k1 = *reinterpret_cast<const bf16x8*>(&Ks[c * 16 + lq][8 * lg + 32]);
#pragma unroll
        for (int rt = 0; rt < 2; ++rt) {
          sc[rt][c] = MFMA32(k0, qf[rt][0], sc[rt][c]);
          sc[rt][c] = MFMA32(k1, qf[rt][1], sc[rt][c]);
        }
      }

      // causal mask (diagonal-region tiles only)
      if (kvb + KVBLK - 1 > wq) {
#pragma unroll
        for (int rt = 0; rt < 2; ++rt) {
          const int q0 = wq + rt * 16 + lq;
#pragma unroll
          for (int c = 0; c < 4; ++c)
#pragma unroll
            for (int r = 0; r < 4; ++r)
              if (kvb + c * 16 + 4 * lg + r > q0) sc[rt][c][r] = -1e30f;
        }
      }

      // ---- online softmax (per q-row = lane lq), P stays in registers ----
      bf16x4 pf[2][4];
      float alpha[2];
#pragma unroll
      for (int rt = 0; rt < 2; ++rt) {
        float c0 = fmaxf(fmaxf(sc[rt][0][0], sc[rt][0][1]), fmaxf(sc[rt][0][2], sc[rt][0][3]));
        float c1 = fmaxf(fmaxf(sc[rt][1][0], sc[rt][1][1]), fmaxf(sc[rt][1][2], sc[rt][1][3]));
        float c2 = fmaxf(fmaxf(sc[rt][2][0], sc[rt][2][1]), fmaxf(sc[rt][2][2], sc[rt][2][3]));
        float c3 = fmaxf(fmaxf(sc[rt][3][0], sc[rt][3][1]), fmaxf(sc[rt][3][2], sc[rt][3][3]));
        float tm = fmaxf(fmaxf(c0, c1), fmaxf(c2, c3));
        tm = fmaxf(tm, __shfl_xor(tm, 16));
        tm = fmaxf(tm, __shfl_xor(tm, 32));
        const float newm = fmaxf(mrun[rt], tm);
        alpha[rt] = EXP2F(mrun[rt] - newm);
        mrun[rt] = newm;

        float ts = 0.f;
#pragma unroll
        for (int c = 0; c < 4; ++c) {
          float p0 = EXP2F(sc[rt][c][0] - newm);
          float p1 = EXP2F(sc[rt][c][1] - newm);
          float p2 = EXP2F(sc[rt][c][2] - newm);
          float p3 = EXP2F(sc[rt][c][3] - newm);
          ts += (p0 + p1) + (p2 + p3);
          union { bf16x4 v; int w[2]; } pp;
          pp.w[0] = f2bf2(p0, p1);
          pp.w[1] = f2bf2(p2, p3);
          pf[rt][c] = pp.v;
        }
        ts += __shfl_xor(ts, 16);
        ts += __shfl_xor(ts, 32);
        lrun[rt] = lrun[rt] * alpha[rt] + ts;
      }

      // ---- rescale acc: alpha lives per q=lq, acc rows are q=4*lg+r -> fetch via shfl ----
#pragma unroll
      for (int rt = 0; rt < 2; ++rt) {
        const float a0 = __shfl(alpha[rt], 4 * lg + 0);
        const float a1 = __shfl(alpha[rt], 4 * lg + 1);
        const float a2 = __shfl(alpha[rt], 4 * lg + 2);
        const float a3 = __shfl(alpha[rt], 4 * lg + 3);
#pragma unroll
        for (int dt = 0; dt < 4; ++dt) {
          acc[rt][dt][0] *= a0;
          acc[rt][dt][1] *= a1;
          acc[rt][dt][2] *= a2;
          acc[rt][dt][3] *= a3;
        }
      }

      // ---- PV: A=P from regs, B=V from VT (contiguous b64 reads), C[q=4*lg+r][d=lq] ----
#pragma unroll
      for (int dt = 0; dt < 4; ++dt) {
#pragma unroll
        for (int c = 0; c < 4; ++c) {
          bf16x4 vf = *reinterpret_cast<const bf16x4*>(&VTs[dt * 16 + lq][c * 16 + 4 * lg]);
          acc[0][dt] = MFMA16(pf[0][c], vf, acc[0][dt]);
          acc[1][dt] = MFMA16(pf[1][c], vf, acc[1][dt]);
        }
      }
    }

    // ---- epilogue: normalize and store (fp32 out) ----
#pragma unroll
    for (int rt = 0; rt < 2; ++rt) {
      const float l0 = __shfl(lrun[rt], 4 * lg + 0);
      const float l1 = __shfl(lrun[rt], 4 * lg + 1);
      const float l2 = __shfl(lrun[rt], 4 * lg + 2);
      const float l3 = __shfl(lrun[rt], 4 * lg + 3);
      const f32x4 linv = {1.f / l0, 1.f / l1, 1.f / l2, 1.f / l3};
#pragma unroll
      for (int dt = 0; dt < 4; ++dt) {
#pragma unroll
        for (int r = 0; r < 4; ++r) {
          out[(size_t)(b * S_LEN + wq + rt * 16 + 4 * lg + r) * (NHEAD * HDIM) + h * HDIM + dt * 16 + lq] =
              acc[rt][dt][r] * linv[r];
        }
      }
    }
  }
}

extern "C" void kernel_launch(void* const* d_in, const int* in_sizes, int n_in,
                              void* d_out, int out_size, void* d_ws, size_t ws_size,
                              hipStream_t stream) {
  const float* qkv = (const float*)d_in[0];
  float* o = (float*)d_out;
  dim3 grid(NQT / 2, 2 * NHEAD);  // paired q-tiles x (B*H)
  attn_fwd<<<grid, 256, 0, stream>>>(qkv, o);
}